// Round 4
// baseline (135.485 us; speedup 1.0000x reference)
//
#include <hip/hip_runtime.h>
#include <math.h>

#define B_DIM 1024
#define D_DIM 512
#define H_DIM 128
#define S_DIM 511
#define PI_F 3.14159265358979323846f
#define ZSWZ_BYTES (8u * 1024u * 128u)      /* 1 MiB: z bf16, swizzle-baked */
#define NTILES_TOTAL 2296                    /* sum over s of ceil((s+1)/64) */
#define W1BF_BYTES ((size_t)NTILES_TOTAL * 16384)

typedef __attribute__((ext_vector_type(8))) short short8;
typedef __attribute__((ext_vector_type(4))) float f32x4;

static __device__ __forceinline__ unsigned cvt_pk_bf16(float lo, float hi) {
    unsigned r;
    asm("v_cvt_pk_bf16_f32 %0, %1, %2" : "=v"(r) : "v"(lo), "v"(hi));
    return r;
}

// tiles before site s in the triangular-packed W1bf buffer
static __device__ __host__ __forceinline__ int tiles_before(int s) {
    const int q = s >> 6, r = s & 63;
    return s + 32 * q * (q - 1) + q * r;
}

// ---------------------------------------------------------------------------
// Pack kernel. Blocks [0,256): z f32 -> bf16 swizzled tiles (A operand).
// Blocks [256,...): W1 f32 [k][h] -> bf16 [h][k] swizzled tiles (B operand),
// triangular-packed, mask (k>s -> 0) baked in. float2 loads: each wave reads
// a full 512B W1 row per instruction (perfect coalescing).
// ---------------------------------------------------------------------------
__global__ __launch_bounds__(256) void pack_kernel(
        const float* __restrict__ z, const float* __restrict__ W1,
        unsigned char* __restrict__ z_swz, unsigned char* __restrict__ w1bf)
{
    if (blockIdx.x < 256) {
        const int gid = blockIdx.x * 256 + threadIdx.x;   // 65536 threads
        const int g   = gid & 7;
        const int row = (gid >> 3) & 1023;
        const int kt  = gid >> 13;
        const int srcg = g ^ (row & 7);
        const float* src = z + (size_t)row * D_DIM + kt * 64 + srcg * 8;
        float4 a = *(const float4*)src;
        float4 b = *(const float4*)(src + 4);
        uint4 w;
        w.x = cvt_pk_bf16(a.x, a.y);
        w.y = cvt_pk_bf16(a.z, a.w);
        w.z = cvt_pk_bf16(b.x, b.y);
        w.w = cvt_pk_bf16(b.z, b.w);
        *(uint4*)(z_swz + (size_t)kt * 131072 + row * 128 + g * 16) = w;
        return;
    }
    const int tb = blockIdx.x - 256;          // 0..4087
    const int s  = tb >> 3;
    const int kk = tb & 7;
    if (s >= S_DIM || kk > (s >> 6)) return;  // kk < ntiles(s) = (s>>6)+1
    const int k0 = kk << 6;
    const int t  = threadIdx.x;
    const int h2 = t & 63;                    // h pair: h = 2*h2, 2*h2+1
    const int mw = t >> 6;                    // wave id -> m = mw, mw+4
    const float* __restrict__ W1s = W1 + (size_t)s * (D_DIM * H_DIM);
    unsigned char* out = w1bf + (size_t)(tiles_before(s) + kk) * 16384;
    const int h0 = h2 * 2, h1 = h2 * 2 + 1;
#pragma unroll
    for (int half = 0; half < 2; ++half) {
        const int m = mw + half * 4;          // 0..7: k-subrange m*8..m*8+7
        float2 v[8];
#pragma unroll
        for (int e = 0; e < 8; ++e) {
            const int gk = k0 + m * 8 + e;
            v[e] = (gk <= s) ? *(const float2*)(W1s + (size_t)gk * H_DIM + h0)
                             : (float2){0.f, 0.f};
        }
        uint4 w0, w1;
        w0.x = cvt_pk_bf16(v[0].x, v[1].x); w0.y = cvt_pk_bf16(v[2].x, v[3].x);
        w0.z = cvt_pk_bf16(v[4].x, v[5].x); w0.w = cvt_pk_bf16(v[6].x, v[7].x);
        w1.x = cvt_pk_bf16(v[0].y, v[1].y); w1.y = cvt_pk_bf16(v[2].y, v[3].y);
        w1.z = cvt_pk_bf16(v[4].y, v[5].y); w1.w = cvt_pk_bf16(v[6].y, v[7].y);
        *(uint4*)(out + h0 * 128 + ((m ^ (h0 & 7)) << 4)) = w0;
        *(uint4*)(out + h1 * 128 + ((m ^ (h1 & 7)) << 4)) = w1;
    }
}

// ---------------------------------------------------------------------------
// Main site kernel, m97-style double-buffered: issue next tile's
// global_load_lds BEFORE computing current tile; one barrier per tile.
// ---------------------------------------------------------------------------
template<bool PRE>
__global__ __launch_bounds__(256) void ar_site_kernel(
        const float* __restrict__ z, const unsigned char* __restrict__ z_swz,
        const unsigned char* __restrict__ w1bf,
        const float* __restrict__ W1, const float* __restrict__ b1,
        const float* __restrict__ W2, const float* __restrict__ b2,
        float* __restrict__ x_out, float* __restrict__ ld_part,
        float* __restrict__ ld_out)
{
    __shared__ __align__(16) unsigned char lds[65536];  // [A0 B0 A1 B1] x 16KB

    // XCD grouping: 8 b-blocks of one site share blockIdx%8 -> same XCD L2.
    const int ib    = blockIdx.x;
    const int s_idx = ((ib >> 6) << 3) | (ib & 7);
    if (s_idx >= S_DIM) return;
    const int s     = S_DIM - 1 - s_idx;                // descending K
    const int bblk  = (ib >> 3) & 7;
    const int brow0 = bblk * 128;
    const int K     = s + 1;
    const int idx   = s + 1;
    const int tid   = threadIdx.x;
    const int lane  = tid & 63;
    const int wid   = tid >> 6;
    const int wr    = wid >> 1;
    const int wc    = wid & 1;
    const int l15   = lane & 15;
    const int l16   = lane >> 4;

    const float* __restrict__ W1s = W1 + (size_t)s * (D_DIM * H_DIM);
    const unsigned char* __restrict__ w1tile =
        PRE ? (w1bf + (size_t)tiles_before(s) * 16384) : nullptr;

    f32x4 acc[4][4];
#pragma unroll
    for (int mi = 0; mi < 4; ++mi)
#pragma unroll
        for (int ni = 0; ni < 4; ++ni)
            acc[mi][ni] = (f32x4){0.f, 0.f, 0.f, 0.f};

    const int ntiles = (K + 63) >> 6;

    if (PRE) {
        // ---- stage tile kk into buffer buf (A at buf*32768, B at buf*32768+16384)
        auto stage = [&](int kk, int buf) {
            const unsigned char* srcA = z_swz + (size_t)kk * 131072 + (size_t)brow0 * 128
                                        + wid * 4096 + lane * 16;
            const unsigned char* srcB = w1tile + (size_t)kk * 16384 + wid * 4096 + lane * 16;
            unsigned char* dstA = lds + buf * 32768 + wid * 4096;
            unsigned char* dstB = lds + buf * 32768 + 16384 + wid * 4096;
#pragma unroll
            for (int i2 = 0; i2 < 4; ++i2) {
                __builtin_amdgcn_global_load_lds(
                    (const __attribute__((address_space(1))) unsigned int*)(srcA + i2 * 1024),
                    (__attribute__((address_space(3))) unsigned int*)(dstA + i2 * 1024),
                    16, 0, 0);
                __builtin_amdgcn_global_load_lds(
                    (const __attribute__((address_space(1))) unsigned int*)(srcB + i2 * 1024),
                    (__attribute__((address_space(3))) unsigned int*)(dstB + i2 * 1024),
                    16, 0, 0);
            }
        };

        stage(0, 0);
        __syncthreads();                       // vmcnt(0) drained before barrier
        int cur = 0;
        for (int kk = 0; kk < ntiles; ++kk) {
            if (kk + 1 < ntiles) stage(kk + 1, cur ^ 1);   // prefetch next tile
            const unsigned char* bufp = lds + cur * 32768;
#pragma unroll
            for (int ks = 0; ks < 2; ++ks) {
                const int kb = ks * 64 + l16 * 16;
                short8 af[4], bfr[4];
#pragma unroll
                for (int mi = 0; mi < 4; ++mi) {
                    const int r = wr * 64 + mi * 16 + l15;
                    af[mi] = *(const short8*)(bufp + r * 128 + (kb ^ ((r & 7) << 4)));
                }
#pragma unroll
                for (int ni = 0; ni < 4; ++ni) {
                    const int h = wc * 64 + ni * 16 + l15;
                    bfr[ni] = *(const short8*)(bufp + 16384 + h * 128 + (kb ^ ((h & 7) << 4)));
                }
#pragma unroll
                for (int mi = 0; mi < 4; ++mi)
#pragma unroll
                    for (int ni = 0; ni < 4; ++ni)
                        acc[mi][ni] = __builtin_amdgcn_mfma_f32_16x16x32_bf16(
                            af[mi], bfr[ni], acc[mi][ni], 0, 0, 0);
            }
            __syncthreads();                   // drains prefetch vmcnt + lgkm
            cur ^= 1;
        }
    } else {
        // legacy single-buffer fallback (d_ws too small): convert in-kernel
        for (int kk = 0; kk < ntiles; ++kk) {
            const int k0 = kk << 6;
            const int g  = tid & 7;
            const int rb = tid >> 3;
#pragma unroll
            for (int p = 0; p < 4; ++p) {
                const int row  = p * 32 + rb;
                const int srcg = g ^ (row & 7);
                const float* zp = z + (size_t)(brow0 + row) * D_DIM + k0 + srcg * 8;
                float4 va = *(const float4*)zp;
                float4 vb = *(const float4*)(zp + 4);
                uint4 w;
                w.x = cvt_pk_bf16(va.x, va.y);
                w.y = cvt_pk_bf16(va.z, va.w);
                w.z = cvt_pk_bf16(vb.x, vb.y);
                w.w = cvt_pk_bf16(vb.z, vb.w);
                *(uint4*)(lds + row * 128 + g * 16) = w;
            }
            const int hgrp  = tid & 31;
            const int kgrp  = tid >> 5;
            const int kbase = k0 + kgrp * 8;
            const float* wp = W1s + (size_t)kbase * H_DIM + hgrp * 4;
            float4 c[8];
#pragma unroll
            for (int j = 0; j < 8; ++j) {
                float4 v = *(const float4*)(wp + (size_t)j * H_DIM);
                const bool ok = (kbase + j) < K;
                v.x = ok ? v.x : 0.f;  v.y = ok ? v.y : 0.f;
                v.z = ok ? v.z : 0.f;  v.w = ok ? v.w : 0.f;
                c[j] = v;
            }
            const float* cf = (const float*)c;
#pragma unroll
            for (int i2 = 0; i2 < 4; ++i2) {
                const int h = hgrp * 4 + i2;
                uint4 w;
                w.x = cvt_pk_bf16(cf[0 * 4 + i2], cf[1 * 4 + i2]);
                w.y = cvt_pk_bf16(cf[2 * 4 + i2], cf[3 * 4 + i2]);
                w.z = cvt_pk_bf16(cf[4 * 4 + i2], cf[5 * 4 + i2]);
                w.w = cvt_pk_bf16(cf[6 * 4 + i2], cf[7 * 4 + i2]);
                *(uint4*)(lds + 16384 + h * 128 + ((kgrp * 16) ^ ((h & 7) << 4))) = w;
            }
            __syncthreads();
#pragma unroll
            for (int ks = 0; ks < 2; ++ks) {
                const int kb = ks * 64 + l16 * 16;
                short8 af[4], bfr[4];
#pragma unroll
                for (int mi = 0; mi < 4; ++mi) {
                    const int r = wr * 64 + mi * 16 + l15;
                    af[mi] = *(const short8*)(lds + r * 128 + (kb ^ ((r & 7) << 4)));
                }
#pragma unroll
                for (int ni = 0; ni < 4; ++ni) {
                    const int h = wc * 64 + ni * 16 + l15;
                    bfr[ni] = *(const short8*)(lds + 16384 + h * 128 + (kb ^ ((h & 7) << 4)));
                }
#pragma unroll
                for (int mi = 0; mi < 4; ++mi)
#pragma unroll
                    for (int ni = 0; ni < 4; ++ni)
                        acc[mi][ni] = __builtin_amdgcn_mfma_f32_16x16x32_bf16(
                            af[mi], bfr[ni], acc[mi][ni], 0, 0, 0);
            }
            __syncthreads();
        }
    }

    // ---- epilogue: h = relu(acc + b1); per-lane partials of p = h @ W2
    float b1v[4], w2a[4], w2b[4];
#pragma unroll
    for (int ni = 0; ni < 4; ++ni) {
        const int c = wc * 64 + ni * 16 + l15;
        b1v[ni] = b1[(size_t)s * H_DIM + c];
        const float* w2p = W2 + ((size_t)s * H_DIM + c) * 2;
        w2a[ni] = w2p[0];
        w2b[ni] = w2p[1];
    }
#pragma unroll
    for (int mi = 0; mi < 4; ++mi) {
#pragma unroll
        for (int r = 0; r < 4; ++r) {
            float p0 = 0.f, p1 = 0.f;
#pragma unroll
            for (int ni = 0; ni < 4; ++ni) {
                float h = acc[mi][ni][r] + b1v[ni];
                h = fmaxf(h, 0.f);
                p0 = fmaf(h, w2a[ni], p0);
                p1 = fmaf(h, w2b[ni], p1);
            }
            const int row = wr * 64 + mi * 16 + l16 * 4 + r;
            const int sw  = (row & 15) << 4;
            *(float*)(lds + row * 256 + ((wc * 128 + l15 * 4) ^ sw))      = p0;
            *(float*)(lds + row * 256 + ((wc * 128 + 64 + l15 * 4) ^ sw)) = p1;
        }
    }
    __syncthreads();

    // ---- reduce partials, NCP transform, write x column + ld partial
    if (tid < 128) {
        const int row = tid;
        const int sw  = (row & 15) << 4;
        float asum = 0.f, bsum = 0.f;
#pragma unroll
        for (int wcb = 0; wcb < 2; ++wcb) {
#pragma unroll
            for (int q = 0; q < 4; ++q) {
                f32x4 va = *(const f32x4*)(lds + row * 256 + ((wcb * 128 + q * 16) ^ sw));
                f32x4 vb = *(const f32x4*)(lds + row * 256 + ((wcb * 128 + 64 + q * 16) ^ sw));
                asum += va.x + va.y + va.z + va.w;
                bsum += vb.x + vb.y + vb.z + vb.w;
            }
        }
        const int grow = brow0 + row;
        const float alpha = asum + b2[(size_t)s * 2 + 0];
        const float beta  = bsum + b2[(size_t)s * 2 + 1];
        const float phi = z[(size_t)grow * D_DIM + idx];
        const float u = tanf(0.5f * (phi - PI_F));
        const float a = expf(alpha);
        const float v = fmaf(a, u, beta);
        x_out[(size_t)grow * D_DIM + idx] = 2.0f * atanf(v) + PI_F;
        const float ld = alpha + log1pf(u * u) - log1pf(v * v);
        if (PRE) ld_part[(size_t)s * B_DIM + grow] = ld;
        else     atomicAdd(ld_out + grow, ld);
    }
}

__global__ __launch_bounds__(256) void ar_finalize(
        const float* __restrict__ z, const float* __restrict__ ld_part,
        float* __restrict__ x_out, float* __restrict__ ld_out, int use_ws)
{
    const int b = blockIdx.x * blockDim.x + threadIdx.x;
    if (b >= B_DIM) return;
    x_out[(size_t)b * D_DIM] = z[(size_t)b * D_DIM];   // untouched column 0
    if (use_ws) {
        float acc = 0.f;
#pragma unroll 8
        for (int i = 0; i < S_DIM; ++i)
            acc += ld_part[(size_t)i * B_DIM + b];
        ld_out[b] = acc;
    }
}

extern "C" void kernel_launch(void* const* d_in, const int* in_sizes, int n_in,
                              void* d_out, int out_size, void* d_ws, size_t ws_size,
                              hipStream_t stream) {
    const float* z  = (const float*)d_in[0];
    const float* W1 = (const float*)d_in[1];
    const float* b1 = (const float*)d_in[2];
    const float* W2 = (const float*)d_in[3];
    const float* b2 = (const float*)d_in[4];
    float* x_out  = (float*)d_out;
    float* ld_out = x_out + (size_t)B_DIM * D_DIM;

    unsigned char* z_swz = (unsigned char*)d_ws;
    unsigned char* w1bf  = z_swz + ZSWZ_BYTES;
    float* ld_part = (float*)(w1bf + W1BF_BYTES);
    const size_t need = ZSWZ_BYTES + W1BF_BYTES + (size_t)S_DIM * B_DIM * sizeof(float);

    if (ws_size >= need) {
        pack_kernel<<<dim3(256 + 4088), dim3(256), 0, stream>>>(z, W1, z_swz, w1bf);
        ar_site_kernel<true><<<dim3(4096), dim3(256), 0, stream>>>(
            z, z_swz, w1bf, W1, b1, W2, b2, x_out, ld_part, ld_out);
        ar_finalize<<<dim3(4), dim3(256), 0, stream>>>(z, ld_part, x_out, ld_out, 1);
    } else {
        hipMemsetAsync(ld_out, 0, B_DIM * sizeof(float), stream);
        ar_site_kernel<false><<<dim3(4096), dim3(256), 0, stream>>>(
            z, nullptr, nullptr, W1, b1, W2, b2, x_out, nullptr, ld_out);
        ar_finalize<<<dim3(4), dim3(256), 0, stream>>>(z, nullptr, x_out, ld_out, 0);
    }
}

// Round 5
// 134.963 us; speedup vs baseline: 1.0039x; 1.0039x over previous
//
#include <hip/hip_runtime.h>
#include <math.h>

#define B_DIM 1024
#define D_DIM 512
#define H_DIM 128
#define S_DIM 511
#define PI_F 3.14159265358979323846f
#define ZSWZ_BYTES (8u * 1024u * 128u)      /* 1 MiB: z bf16, swizzle-baked */
#define NTILES_TOTAL 2296                    /* sum over s of ceil((s+1)/64) */
#define W1BF_BYTES ((size_t)NTILES_TOTAL * 16384)

typedef __attribute__((ext_vector_type(8))) short short8;
typedef __attribute__((ext_vector_type(4))) float f32x4;

static __device__ __forceinline__ unsigned cvt_pk_bf16(float lo, float hi) {
    unsigned r;
    asm("v_cvt_pk_bf16_f32 %0, %1, %2" : "=v"(r) : "v"(lo), "v"(hi));
    return r;
}

// tiles before site s in the triangular-packed W1bf buffer
static __device__ __host__ __forceinline__ int tiles_before(int s) {
    const int q = s >> 6, r = s & 63;
    return s + 32 * q * (q - 1) + q * r;
}

// ---------------------------------------------------------------------------
// Pack kernel. Blocks [0,256): z f32 -> bf16 swizzled tiles (A operand).
// Blocks [256,...): W1 f32 [k][h] -> bf16 [h][k] swizzled tiles (B operand),
// triangular-packed, mask (k>s -> 0) baked in.
// ---------------------------------------------------------------------------
__global__ __launch_bounds__(256) void pack_kernel(
        const float* __restrict__ z, const float* __restrict__ W1,
        unsigned char* __restrict__ z_swz, unsigned char* __restrict__ w1bf)
{
    if (blockIdx.x < 256) {
        const int gid = blockIdx.x * 256 + threadIdx.x;   // 65536 threads
        const int g   = gid & 7;
        const int row = (gid >> 3) & 1023;
        const int kt  = gid >> 13;
        const int srcg = g ^ (row & 7);
        const float* src = z + (size_t)row * D_DIM + kt * 64 + srcg * 8;
        float4 a = *(const float4*)src;
        float4 b = *(const float4*)(src + 4);
        uint4 w;
        w.x = cvt_pk_bf16(a.x, a.y);
        w.y = cvt_pk_bf16(a.z, a.w);
        w.z = cvt_pk_bf16(b.x, b.y);
        w.w = cvt_pk_bf16(b.z, b.w);
        *(uint4*)(z_swz + (size_t)kt * 131072 + row * 128 + g * 16) = w;
        return;
    }
    const int tb = blockIdx.x - 256;          // 0..4087
    const int s  = tb >> 3;
    const int kk = tb & 7;
    if (s >= S_DIM || kk > (s >> 6)) return;  // kk < ntiles(s) = (s>>6)+1
    const int k0 = kk << 6;
    const int t  = threadIdx.x;
    const int h2 = t & 63;                    // h pair: h = 2*h2, 2*h2+1
    const int mw = t >> 6;                    // wave id -> m = mw, mw+4
    const float* __restrict__ W1s = W1 + (size_t)s * (D_DIM * H_DIM);
    unsigned char* out = w1bf + (size_t)(tiles_before(s) + kk) * 16384;
    const int h0 = h2 * 2, h1 = h2 * 2 + 1;
#pragma unroll
    for (int half = 0; half < 2; ++half) {
        const int m = mw + half * 4;          // 0..7: k-subrange m*8..m*8+7
        float2 v[8];
#pragma unroll
        for (int e = 0; e < 8; ++e) {
            const int gk = k0 + m * 8 + e;
            v[e] = (gk <= s) ? *(const float2*)(W1s + (size_t)gk * H_DIM + h0)
                             : (float2){0.f, 0.f};
        }
        uint4 w0, w1;
        w0.x = cvt_pk_bf16(v[0].x, v[1].x); w0.y = cvt_pk_bf16(v[2].x, v[3].x);
        w0.z = cvt_pk_bf16(v[4].x, v[5].x); w0.w = cvt_pk_bf16(v[6].x, v[7].x);
        w1.x = cvt_pk_bf16(v[0].y, v[1].y); w1.y = cvt_pk_bf16(v[2].y, v[3].y);
        w1.z = cvt_pk_bf16(v[4].y, v[5].y); w1.w = cvt_pk_bf16(v[6].y, v[7].y);
        *(uint4*)(out + h0 * 128 + ((m ^ (h0 & 7)) << 4)) = w0;
        *(uint4*)(out + h1 * 128 + ((m ^ (h1 & 7)) << 4)) = w1;
    }
}

// ---------------------------------------------------------------------------
// Main site kernel: double-buffered, depth-2 prefetch, COUNTED vmcnt(8)
// (never 0 in steady state) + raw s_barrier — loads stay in flight across
// barriers (T3/T4). setprio(1) around the MFMA cluster (T5).
// ---------------------------------------------------------------------------
template<bool PRE>
__global__ __launch_bounds__(256) void ar_site_kernel(
        const float* __restrict__ z, const unsigned char* __restrict__ z_swz,
        const unsigned char* __restrict__ w1bf,
        const float* __restrict__ W1, const float* __restrict__ b1,
        const float* __restrict__ W2, const float* __restrict__ b2,
        float* __restrict__ x_out, float* __restrict__ ld_part,
        float* __restrict__ ld_out)
{
    __shared__ __align__(16) unsigned char lds[65536];  // [A0 B0 | A1 B1] x 32KB

    // XCD grouping: 8 b-blocks of one site share blockIdx%8 -> same XCD L2.
    const int ib    = blockIdx.x;
    const int s_idx = ((ib >> 6) << 3) | (ib & 7);
    if (s_idx >= S_DIM) return;
    const int s     = S_DIM - 1 - s_idx;                // descending K
    const int bblk  = (ib >> 3) & 7;
    const int brow0 = bblk * 128;
    const int K     = s + 1;
    const int idx   = s + 1;
    const int tid   = threadIdx.x;
    const int lane  = tid & 63;
    const int wid   = tid >> 6;
    const int wr    = wid >> 1;
    const int wc    = wid & 1;
    const int l15   = lane & 15;
    const int l16   = lane >> 4;

    const float* __restrict__ W1s = W1 + (size_t)s * (D_DIM * H_DIM);
    const unsigned char* __restrict__ w1tile =
        PRE ? (w1bf + (size_t)tiles_before(s) * 16384) : nullptr;

    f32x4 acc[4][4];
#pragma unroll
    for (int mi = 0; mi < 4; ++mi)
#pragma unroll
        for (int ni = 0; ni < 4; ++ni)
            acc[mi][ni] = (f32x4){0.f, 0.f, 0.f, 0.f};

    const int ntiles = (K + 63) >> 6;

    if (PRE) {
        auto stage = [&](int kk, int buf) {
            const unsigned char* srcA = z_swz + (size_t)kk * 131072 + (size_t)brow0 * 128
                                        + wid * 4096 + lane * 16;
            const unsigned char* srcB = w1tile + (size_t)kk * 16384 + wid * 4096 + lane * 16;
            unsigned char* dstA = lds + buf * 32768 + wid * 4096;
            unsigned char* dstB = lds + buf * 32768 + 16384 + wid * 4096;
#pragma unroll
            for (int i2 = 0; i2 < 4; ++i2) {
                __builtin_amdgcn_global_load_lds(
                    (const __attribute__((address_space(1))) unsigned int*)(srcA + i2 * 1024),
                    (__attribute__((address_space(3))) unsigned int*)(dstA + i2 * 1024),
                    16, 0, 0);
                __builtin_amdgcn_global_load_lds(
                    (const __attribute__((address_space(1))) unsigned int*)(srcB + i2 * 1024),
                    (__attribute__((address_space(3))) unsigned int*)(dstB + i2 * 1024),
                    16, 0, 0);
            }
        };

        stage(0, 0);
        if (ntiles > 1) stage(1, 1);          // 16 loads in flight max
        int cur = 0;
        for (int kk = 0; kk < ntiles; ++kk) {
            // tile kk landed when <=8 outstanding (tile kk+1's); oldest-first
            // drain (m135) guarantees it. Each wave checks its OWN loads, so
            // after the barrier every wave's tile-kk data is in LDS.
            if (kk + 1 < ntiles) {
                asm volatile("s_waitcnt vmcnt(8)" ::: "memory");
            } else {
                asm volatile("s_waitcnt vmcnt(0)" ::: "memory");
            }
            __builtin_amdgcn_s_barrier();
            __builtin_amdgcn_sched_barrier(0);   // no ds_read hoisted above
            const unsigned char* bufp = lds + cur * 32768;
#pragma unroll
            for (int ks = 0; ks < 2; ++ks) {
                const int kb = ks * 64 + l16 * 16;
                short8 af[4], bfr[4];
#pragma unroll
                for (int mi = 0; mi < 4; ++mi) {
                    const int r = wr * 64 + mi * 16 + l15;
                    af[mi] = *(const short8*)(bufp + r * 128 + (kb ^ ((r & 7) << 4)));
                }
#pragma unroll
                for (int ni = 0; ni < 4; ++ni) {
                    const int h = wc * 64 + ni * 16 + l15;
                    bfr[ni] = *(const short8*)(bufp + 16384 + h * 128 + (kb ^ ((h & 7) << 4)));
                }
                __builtin_amdgcn_s_setprio(1);
#pragma unroll
                for (int mi = 0; mi < 4; ++mi)
#pragma unroll
                    for (int ni = 0; ni < 4; ++ni)
                        acc[mi][ni] = __builtin_amdgcn_mfma_f32_16x16x32_bf16(
                            af[mi], bfr[ni], acc[mi][ni], 0, 0, 0);
                __builtin_amdgcn_s_setprio(0);
            }
            // all waves done reading buf[cur] (ds_reads consumed pre-barrier)
            __builtin_amdgcn_s_barrier();
            if (kk + 2 < ntiles) stage(kk + 2, cur);   // refill consumed buffer
            cur ^= 1;
        }
    } else {
        // legacy single-buffer fallback (d_ws too small): convert in-kernel
        for (int kk = 0; kk < ntiles; ++kk) {
            const int k0 = kk << 6;
            const int g  = tid & 7;
            const int rb = tid >> 3;
#pragma unroll
            for (int p = 0; p < 4; ++p) {
                const int row  = p * 32 + rb;
                const int srcg = g ^ (row & 7);
                const float* zp = z + (size_t)(brow0 + row) * D_DIM + k0 + srcg * 8;
                float4 va = *(const float4*)zp;
                float4 vb = *(const float4*)(zp + 4);
                uint4 w;
                w.x = cvt_pk_bf16(va.x, va.y);
                w.y = cvt_pk_bf16(va.z, va.w);
                w.z = cvt_pk_bf16(vb.x, vb.y);
                w.w = cvt_pk_bf16(vb.z, vb.w);
                *(uint4*)(lds + row * 128 + g * 16) = w;
            }
            const int hgrp  = tid & 31;
            const int kgrp  = tid >> 5;
            const int kbase = k0 + kgrp * 8;
            const float* wp = W1s + (size_t)kbase * H_DIM + hgrp * 4;
            float4 c[8];
#pragma unroll
            for (int j = 0; j < 8; ++j) {
                float4 v = *(const float4*)(wp + (size_t)j * H_DIM);
                const bool ok = (kbase + j) < K;
                v.x = ok ? v.x : 0.f;  v.y = ok ? v.y : 0.f;
                v.z = ok ? v.z : 0.f;  v.w = ok ? v.w : 0.f;
                c[j] = v;
            }
            const float* cf = (const float*)c;
#pragma unroll
            for (int i2 = 0; i2 < 4; ++i2) {
                const int h = hgrp * 4 + i2;
                uint4 w;
                w.x = cvt_pk_bf16(cf[0 * 4 + i2], cf[1 * 4 + i2]);
                w.y = cvt_pk_bf16(cf[2 * 4 + i2], cf[3 * 4 + i2]);
                w.z = cvt_pk_bf16(cf[4 * 4 + i2], cf[5 * 4 + i2]);
                w.w = cvt_pk_bf16(cf[6 * 4 + i2], cf[7 * 4 + i2]);
                *(uint4*)(lds + 16384 + h * 128 + ((kgrp * 16) ^ ((h & 7) << 4))) = w;
            }
            __syncthreads();
#pragma unroll
            for (int ks = 0; ks < 2; ++ks) {
                const int kb = ks * 64 + l16 * 16;
                short8 af[4], bfr[4];
#pragma unroll
                for (int mi = 0; mi < 4; ++mi) {
                    const int r = wr * 64 + mi * 16 + l15;
                    af[mi] = *(const short8*)(lds + r * 128 + (kb ^ ((r & 7) << 4)));
                }
#pragma unroll
                for (int ni = 0; ni < 4; ++ni) {
                    const int h = wc * 64 + ni * 16 + l15;
                    bfr[ni] = *(const short8*)(lds + 16384 + h * 128 + (kb ^ ((h & 7) << 4)));
                }
#pragma unroll
                for (int mi = 0; mi < 4; ++mi)
#pragma unroll
                    for (int ni = 0; ni < 4; ++ni)
                        acc[mi][ni] = __builtin_amdgcn_mfma_f32_16x16x32_bf16(
                            af[mi], bfr[ni], acc[mi][ni], 0, 0, 0);
            }
            __syncthreads();
        }
    }

    // ---- epilogue: h = relu(acc + b1); per-lane partials of p = h @ W2
    float b1v[4], w2a[4], w2b[4];
#pragma unroll
    for (int ni = 0; ni < 4; ++ni) {
        const int c = wc * 64 + ni * 16 + l15;
        b1v[ni] = b1[(size_t)s * H_DIM + c];
        const float* w2p = W2 + ((size_t)s * H_DIM + c) * 2;
        w2a[ni] = w2p[0];
        w2b[ni] = w2p[1];
    }
#pragma unroll
    for (int mi = 0; mi < 4; ++mi) {
#pragma unroll
        for (int r = 0; r < 4; ++r) {
            float p0 = 0.f, p1 = 0.f;
#pragma unroll
            for (int ni = 0; ni < 4; ++ni) {
                float h = acc[mi][ni][r] + b1v[ni];
                h = fmaxf(h, 0.f);
                p0 = fmaf(h, w2a[ni], p0);
                p1 = fmaf(h, w2b[ni], p1);
            }
            const int row = wr * 64 + mi * 16 + l16 * 4 + r;
            const int sw  = (row & 15) << 4;
            *(float*)(lds + row * 256 + ((wc * 128 + l15 * 4) ^ sw))      = p0;
            *(float*)(lds + row * 256 + ((wc * 128 + 64 + l15 * 4) ^ sw)) = p1;
        }
    }
    __syncthreads();

    // ---- reduce partials, NCP transform, write x column + ld partial
    if (tid < 128) {
        const int row = tid;
        const int sw  = (row & 15) << 4;
        float asum = 0.f, bsum = 0.f;
#pragma unroll
        for (int wcb = 0; wcb < 2; ++wcb) {
#pragma unroll
            for (int q = 0; q < 4; ++q) {
                f32x4 va = *(const f32x4*)(lds + row * 256 + ((wcb * 128 + q * 16) ^ sw));
                f32x4 vb = *(const f32x4*)(lds + row * 256 + ((wcb * 128 + 64 + q * 16) ^ sw));
                asum += va.x + va.y + va.z + va.w;
                bsum += vb.x + vb.y + vb.z + vb.w;
            }
        }
        const int grow = brow0 + row;
        const float alpha = asum + b2[(size_t)s * 2 + 0];
        const float beta  = bsum + b2[(size_t)s * 2 + 1];
        const float phi = z[(size_t)grow * D_DIM + idx];
        const float u = tanf(0.5f * (phi - PI_F));
        const float a = expf(alpha);
        const float v = fmaf(a, u, beta);
        x_out[(size_t)grow * D_DIM + idx] = 2.0f * atanf(v) + PI_F;
        const float ld = alpha + log1pf(u * u) - log1pf(v * v);
        if (PRE) ld_part[(size_t)s * B_DIM + grow] = ld;
        else     atomicAdd(ld_out + grow, ld);
    }
}

__global__ __launch_bounds__(256) void ar_finalize(
        const float* __restrict__ z, const float* __restrict__ ld_part,
        float* __restrict__ x_out, float* __restrict__ ld_out, int use_ws)
{
    const int b = blockIdx.x * blockDim.x + threadIdx.x;
    if (b >= B_DIM) return;
    x_out[(size_t)b * D_DIM] = z[(size_t)b * D_DIM];   // untouched column 0
    if (use_ws) {
        float acc = 0.f;
#pragma unroll 8
        for (int i = 0; i < S_DIM; ++i)
            acc += ld_part[(size_t)i * B_DIM + b];
        ld_out[b] = acc;
    }
}

extern "C" void kernel_launch(void* const* d_in, const int* in_sizes, int n_in,
                              void* d_out, int out_size, void* d_ws, size_t ws_size,
                              hipStream_t stream) {
    const float* z  = (const float*)d_in[0];
    const float* W1 = (const float*)d_in[1];
    const float* b1 = (const float*)d_in[2];
    const float* W2 = (const float*)d_in[3];
    const float* b2 = (const float*)d_in[4];
    float* x_out  = (float*)d_out;
    float* ld_out = x_out + (size_t)B_DIM * D_DIM;

    unsigned char* z_swz = (unsigned char*)d_ws;
    unsigned char* w1bf  = z_swz + ZSWZ_BYTES;
    float* ld_part = (float*)(w1bf + W1BF_BYTES);
    const size_t need = ZSWZ_BYTES + W1BF_BYTES + (size_t)S_DIM * B_DIM * sizeof(float);

    if (ws_size >= need) {
        pack_kernel<<<dim3(256 + 4088), dim3(256), 0, stream>>>(z, W1, z_swz, w1bf);
        ar_site_kernel<true><<<dim3(4096), dim3(256), 0, stream>>>(
            z, z_swz, w1bf, W1, b1, W2, b2, x_out, ld_part, ld_out);
        ar_finalize<<<dim3(4), dim3(256), 0, stream>>>(z, ld_part, x_out, ld_out, 1);
    } else {
        hipMemsetAsync(ld_out, 0, B_DIM * sizeof(float), stream);
        ar_site_kernel<false><<<dim3(4096), dim3(256), 0, stream>>>(
            z, nullptr, nullptr, W1, b1, W2, b2, x_out, nullptr, ld_out);
        ar_finalize<<<dim3(4), dim3(256), 0, stream>>>(z, nullptr, x_out, ld_out, 0);
    }
}

// Round 6
// 107.326 us; speedup vs baseline: 1.2624x; 1.2575x over previous
//
#include <hip/hip_runtime.h>
#include <math.h>

#define B_DIM 1024
#define D_DIM 512
#define H_DIM 128
#define S_DIM 511
#define PI_F 3.14159265358979323846f
#define ZSWZ_BYTES (8u * 1024u * 128u)      /* 1 MiB: z bf16, swizzle-baked */
#define NTILES_TOTAL 2296                    /* sum over s of ceil((s+1)/64) */
#define W1BF_BYTES ((size_t)NTILES_TOTAL * 16384)

typedef __attribute__((ext_vector_type(8))) short short8;
typedef __attribute__((ext_vector_type(4))) float f32x4;

static __device__ __forceinline__ unsigned cvt_pk_bf16(float lo, float hi) {
    unsigned r;
    asm("v_cvt_pk_bf16_f32 %0, %1, %2" : "=v"(r) : "v"(lo), "v"(hi));
    return r;
}

// tiles before site s in the triangular-packed W1bf buffer
static __device__ __host__ __forceinline__ int tiles_before(int s) {
    const int q = s >> 6, r = s & 63;
    return s + 32 * q * (q - 1) + q * r;
}

// ---------------------------------------------------------------------------
// Pack kernel (unchanged from R5). z -> bf16 swizzled; W1 -> [h][k] bf16
// swizzled triangular-packed tiles with the K-mask baked in.
// ---------------------------------------------------------------------------
__global__ __launch_bounds__(256) void pack_kernel(
        const float* __restrict__ z, const float* __restrict__ W1,
        unsigned char* __restrict__ z_swz, unsigned char* __restrict__ w1bf)
{
    if (blockIdx.x < 256) {
        const int gid = blockIdx.x * 256 + threadIdx.x;   // 65536 threads
        const int g   = gid & 7;
        const int row = (gid >> 3) & 1023;
        const int kt  = gid >> 13;
        const int srcg = g ^ (row & 7);
        const float* src = z + (size_t)row * D_DIM + kt * 64 + srcg * 8;
        float4 a = *(const float4*)src;
        float4 b = *(const float4*)(src + 4);
        uint4 w;
        w.x = cvt_pk_bf16(a.x, a.y);
        w.y = cvt_pk_bf16(a.z, a.w);
        w.z = cvt_pk_bf16(b.x, b.y);
        w.w = cvt_pk_bf16(b.z, b.w);
        *(uint4*)(z_swz + (size_t)kt * 131072 + row * 128 + g * 16) = w;
        return;
    }
    const int tb = blockIdx.x - 256;          // 0..4087
    const int s  = tb >> 3;
    const int kk = tb & 7;
    if (s >= S_DIM || kk > (s >> 6)) return;
    const int k0 = kk << 6;
    const int t  = threadIdx.x;
    const int h2 = t & 63;
    const int mw = t >> 6;
    const float* __restrict__ W1s = W1 + (size_t)s * (D_DIM * H_DIM);
    unsigned char* out = w1bf + (size_t)(tiles_before(s) + kk) * 16384;
    const int h0 = h2 * 2, h1 = h2 * 2 + 1;
#pragma unroll
    for (int half = 0; half < 2; ++half) {
        const int m = mw + half * 4;
        float2 v[8];
#pragma unroll
        for (int e = 0; e < 8; ++e) {
            const int gk = k0 + m * 8 + e;
            v[e] = (gk <= s) ? *(const float2*)(W1s + (size_t)gk * H_DIM + h0)
                             : (float2){0.f, 0.f};
        }
        uint4 w0, w1;
        w0.x = cvt_pk_bf16(v[0].x, v[1].x); w0.y = cvt_pk_bf16(v[2].x, v[3].x);
        w0.z = cvt_pk_bf16(v[4].x, v[5].x); w0.w = cvt_pk_bf16(v[6].x, v[7].x);
        w1.x = cvt_pk_bf16(v[0].y, v[1].y); w1.y = cvt_pk_bf16(v[2].y, v[3].y);
        w1.z = cvt_pk_bf16(v[4].y, v[5].y); w1.w = cvt_pk_bf16(v[6].y, v[7].y);
        *(uint4*)(out + h0 * 128 + ((m ^ (h0 & 7)) << 4)) = w0;
        *(uint4*)(out + h1 * 128 + ((m ^ (h1 & 7)) << 4)) = w1;
    }
}

// ---------------------------------------------------------------------------
// Chained site kernel (PRE=true): 512 blocks = 64 chains x 8 bblocks, all
// resident (2 blocks/CU, 72KB LDS). Each block streams ~36 (site,kk) tiles
// CONTINUOUSLY through a 2-slot ring with counted vmcnt(8) — pipeline warmup
// paid once per chain, not once per site. Snake site->chain assignment
// balances tile counts; chain c's 8 bblocks share XCD c&7 (W1 L2 reuse).
// PRE=false: legacy one-site-per-block fallback.
// ---------------------------------------------------------------------------
template<bool PRE>
__global__ __launch_bounds__(256) void ar_site_kernel(
        const float* __restrict__ z, const unsigned char* __restrict__ z_swz,
        const unsigned char* __restrict__ w1bf,
        const float* __restrict__ W1, const float* __restrict__ b1,
        const float* __restrict__ W2, const float* __restrict__ b2,
        float* __restrict__ x_out, float* __restrict__ ld_out)
{
    __shared__ __align__(16) unsigned char lds[73728]; // ring 2x32KB + epi 8KB

    const int tid  = threadIdx.x;
    const int lane = tid & 63;
    const int wid  = tid >> 6;
    const int wr   = wid >> 1;
    const int wc   = wid & 1;
    const int l15  = lane & 15;
    const int l16  = lane >> 4;

    if (PRE) {
        const int ib   = blockIdx.x;            // 0..511
        const int c    = (((ib >> 3) & 7) << 3) | (ib & 7);  // chain 0..63
        const int bblk = ib >> 6;               // 0..7
        const int brow0 = bblk * 128;

        // ---- prefetch stream state over (t, kk) of this chain
        int pf_t = 0, pf_kk = 0, pf_step = 0;
        int pf_s = 510 - c;
        int pf_base = tiles_before(pf_s);

        auto pf_stage = [&]() {
            if (pf_t >= 8) return;
            const int slot = pf_step & 1;
            const unsigned char* srcA = z_swz + (size_t)pf_kk * 131072
                                        + (size_t)brow0 * 128 + wid * 4096 + lane * 16;
            const unsigned char* srcB = w1bf + (size_t)(pf_base + pf_kk) * 16384
                                        + wid * 4096 + lane * 16;
            unsigned char* dstA = lds + slot * 32768 + wid * 4096;
            unsigned char* dstB = lds + slot * 32768 + 16384 + wid * 4096;
#pragma unroll
            for (int i2 = 0; i2 < 4; ++i2) {
                __builtin_amdgcn_global_load_lds(
                    (const __attribute__((address_space(1))) unsigned int*)(srcA + i2 * 1024),
                    (__attribute__((address_space(3))) unsigned int*)(dstA + i2 * 1024),
                    16, 0, 0);
                __builtin_amdgcn_global_load_lds(
                    (const __attribute__((address_space(1))) unsigned int*)(srcB + i2 * 1024),
                    (__attribute__((address_space(3))) unsigned int*)(dstB + i2 * 1024),
                    16, 0, 0);
            }
            ++pf_step; ++pf_kk;
            if (pf_kk == ((pf_s >> 6) + 1)) {
                pf_kk = 0; ++pf_t;
                while (pf_t < 8) {
                    const int j = pf_t * 64 + ((pf_t & 1) ? (63 - c) : c);
                    if (j < S_DIM) { pf_s = 510 - j; pf_base = tiles_before(pf_s); break; }
                    ++pf_t;
                }
            }
        };

        int csteps = 0;
#pragma unroll
        for (int t = 0; t < 8; ++t) {
            const int j = t * 64 + ((t & 1) ? (63 - c) : c);
            if (j < S_DIM) csteps += ((510 - j) >> 6) + 1;
        }

        pf_stage();                    // step 0 -> slot 0
        pf_stage();                    // step 1 -> slot 1

        int step = 0;
        float ld_acc = 0.f;

        for (int t = 0; t < 8; ++t) {
            const int j = t * 64 + ((t & 1) ? (63 - c) : c);
            if (j >= S_DIM) continue;
            const int s   = 510 - j;
            const int nt  = (s >> 6) + 1;
            const int idx = s + 1;

            f32x4 acc[4][4];
#pragma unroll
            for (int mi = 0; mi < 4; ++mi)
#pragma unroll
                for (int ni = 0; ni < 4; ++ni)
                    acc[mi][ni] = (f32x4){0.f, 0.f, 0.f, 0.f};

            for (int kk = 0; kk < nt; ++kk) {
                if (step + 1 == csteps) {
                    asm volatile("s_waitcnt vmcnt(0)" ::: "memory");
                } else {
                    asm volatile("s_waitcnt vmcnt(8)" ::: "memory");
                }
                __builtin_amdgcn_s_barrier();
                __builtin_amdgcn_sched_barrier(0);
                const unsigned char* bufp = lds + (step & 1) * 32768;
#pragma unroll
                for (int ks = 0; ks < 2; ++ks) {
                    const int kb = ks * 64 + l16 * 16;
                    short8 af[4], bfr[4];
#pragma unroll
                    for (int mi = 0; mi < 4; ++mi) {
                        const int r = wr * 64 + mi * 16 + l15;
                        af[mi] = *(const short8*)(bufp + r * 128 + (kb ^ ((r & 7) << 4)));
                    }
#pragma unroll
                    for (int ni = 0; ni < 4; ++ni) {
                        const int h = wc * 64 + ni * 16 + l15;
                        bfr[ni] = *(const short8*)(bufp + 16384 + h * 128 + (kb ^ ((h & 7) << 4)));
                    }
                    __builtin_amdgcn_s_setprio(1);
#pragma unroll
                    for (int mi = 0; mi < 4; ++mi)
#pragma unroll
                        for (int ni = 0; ni < 4; ++ni)
                            acc[mi][ni] = __builtin_amdgcn_mfma_f32_16x16x32_bf16(
                                af[mi], bfr[ni], acc[mi][ni], 0, 0, 0);
                    __builtin_amdgcn_s_setprio(0);
                }
                __builtin_amdgcn_s_barrier();
                pf_stage();            // refill the just-consumed slot
                ++step;
            }

            // ---- site epilogue: p = relu(acc+b1) @ W2, then NCP transform
            float b1v[4], w2a[4], w2b[4];
#pragma unroll
            for (int ni = 0; ni < 4; ++ni) {
                const int cc = wc * 64 + ni * 16 + l15;
                b1v[ni] = b1[(size_t)s * H_DIM + cc];
                const float2 w2v = *(const float2*)(W2 + ((size_t)s * H_DIM + cc) * 2);
                w2a[ni] = w2v.x;
                w2b[ni] = w2v.y;
            }
            float p0s[4][4], p1s[4][4];
#pragma unroll
            for (int mi = 0; mi < 4; ++mi)
#pragma unroll
                for (int r = 0; r < 4; ++r) {
                    float p0 = 0.f, p1 = 0.f;
#pragma unroll
                    for (int ni = 0; ni < 4; ++ni) {
                        float h = acc[mi][ni][r] + b1v[ni];
                        h = fmaxf(h, 0.f);
                        p0 = fmaf(h, w2a[ni], p0);
                        p1 = fmaf(h, w2b[ni], p1);
                    }
                    p0s[mi][r] = p0; p1s[mi][r] = p1;
                }
            // reduce over l15 low-2 bits (4 lanes) in-register
#pragma unroll
            for (int mi = 0; mi < 4; ++mi)
#pragma unroll
                for (int r = 0; r < 4; ++r) {
                    p0s[mi][r] += __shfl_xor(p0s[mi][r], 1);
                    p0s[mi][r] += __shfl_xor(p0s[mi][r], 2);
                    p1s[mi][r] += __shfl_xor(p1s[mi][r], 1);
                    p1s[mi][r] += __shfl_xor(p1s[mi][r], 2);
                }
            if ((lane & 3) == 0) {
                const int cw = wc * 4 + (l15 >> 2);
#pragma unroll
                for (int mi = 0; mi < 4; ++mi)
#pragma unroll
                    for (int r = 0; r < 4; ++r) {
                        const int row = wr * 64 + mi * 16 + l16 * 4 + r;
                        *(float2*)(lds + 65536 + (row * 8 + (cw ^ (row & 7))) * 8)
                            = (float2){p0s[mi][r], p1s[mi][r]};
                    }
            }
            asm volatile("s_waitcnt lgkmcnt(0)" ::: "memory");
            __builtin_amdgcn_s_barrier();
            __builtin_amdgcn_sched_barrier(0);
            if (tid < 128) {
                const int row = tid;
                float alpha = b2[(size_t)s * 2 + 0];
                float beta  = b2[(size_t)s * 2 + 1];
#pragma unroll
                for (int cw = 0; cw < 8; ++cw) {
                    const float2 v = *(const float2*)(lds + 65536 + (row * 8 + (cw ^ (row & 7))) * 8);
                    alpha += v.x; beta += v.y;
                }
                const int grow = brow0 + row;
                const float phi = z[(size_t)grow * D_DIM + idx];
                const float u = tanf(0.5f * (phi - PI_F));
                const float a = expf(alpha);
                const float v = fmaf(a, u, beta);
                x_out[(size_t)grow * D_DIM + idx] = 2.0f * atanf(v) + PI_F;
                ld_acc += alpha + log1pf(u * u) - log1pf(v * v);
            }
        }
        if (tid < 128) atomicAdd(ld_out + brow0 + tid, ld_acc);
        if (c == 0 && tid < 128)
            x_out[(size_t)(brow0 + tid) * D_DIM] = z[(size_t)(brow0 + tid) * D_DIM];
        return;
    }

    // ---------------- legacy fallback: one site per block, in-kernel cvt ----
    const int ib    = blockIdx.x;
    const int s_idx = ((ib >> 6) << 3) | (ib & 7);
    if (s_idx >= S_DIM) return;
    const int s     = S_DIM - 1 - s_idx;
    const int bblk  = (ib >> 3) & 7;
    const int brow0 = bblk * 128;
    const int K     = s + 1;
    const int idx   = s + 1;
    const float* __restrict__ W1s = W1 + (size_t)s * (D_DIM * H_DIM);

    f32x4 acc[4][4];
#pragma unroll
    for (int mi = 0; mi < 4; ++mi)
#pragma unroll
        for (int ni = 0; ni < 4; ++ni)
            acc[mi][ni] = (f32x4){0.f, 0.f, 0.f, 0.f};

    const int ntiles = (K + 63) >> 6;
    for (int kk = 0; kk < ntiles; ++kk) {
        const int k0 = kk << 6;
        const int g  = tid & 7;
        const int rb = tid >> 3;
#pragma unroll
        for (int p = 0; p < 4; ++p) {
            const int row  = p * 32 + rb;
            const int srcg = g ^ (row & 7);
            const float* zp = z + (size_t)(brow0 + row) * D_DIM + k0 + srcg * 8;
            float4 va = *(const float4*)zp;
            float4 vb = *(const float4*)(zp + 4);
            uint4 w;
            w.x = cvt_pk_bf16(va.x, va.y);
            w.y = cvt_pk_bf16(va.z, va.w);
            w.z = cvt_pk_bf16(vb.x, vb.y);
            w.w = cvt_pk_bf16(vb.z, vb.w);
            *(uint4*)(lds + row * 128 + g * 16) = w;
        }
        const int hgrp  = tid & 31;
        const int kgrp  = tid >> 5;
        const int kbase = k0 + kgrp * 8;
        const float* wp = W1s + (size_t)kbase * H_DIM + hgrp * 4;
        float4 cc[8];
#pragma unroll
        for (int jj = 0; jj < 8; ++jj) {
            float4 v = *(const float4*)(wp + (size_t)jj * H_DIM);
            const bool ok = (kbase + jj) < K;
            v.x = ok ? v.x : 0.f;  v.y = ok ? v.y : 0.f;
            v.z = ok ? v.z : 0.f;  v.w = ok ? v.w : 0.f;
            cc[jj] = v;
        }
        const float* cf = (const float*)cc;
#pragma unroll
        for (int i2 = 0; i2 < 4; ++i2) {
            const int h = hgrp * 4 + i2;
            uint4 w;
            w.x = cvt_pk_bf16(cf[0 * 4 + i2], cf[1 * 4 + i2]);
            w.y = cvt_pk_bf16(cf[2 * 4 + i2], cf[3 * 4 + i2]);
            w.z = cvt_pk_bf16(cf[4 * 4 + i2], cf[5 * 4 + i2]);
            w.w = cvt_pk_bf16(cf[6 * 4 + i2], cf[7 * 4 + i2]);
            *(uint4*)(lds + 16384 + h * 128 + ((kgrp * 16) ^ ((h & 7) << 4))) = w;
        }
        __syncthreads();
#pragma unroll
        for (int ks = 0; ks < 2; ++ks) {
            const int kb = ks * 64 + l16 * 16;
            short8 af[4], bfr[4];
#pragma unroll
            for (int mi = 0; mi < 4; ++mi) {
                const int r = wr * 64 + mi * 16 + l15;
                af[mi] = *(const short8*)(lds + r * 128 + (kb ^ ((r & 7) << 4)));
            }
#pragma unroll
            for (int ni = 0; ni < 4; ++ni) {
                const int h = wc * 64 + ni * 16 + l15;
                bfr[ni] = *(const short8*)(lds + 16384 + h * 128 + (kb ^ ((h & 7) << 4)));
            }
#pragma unroll
            for (int mi = 0; mi < 4; ++mi)
#pragma unroll
                for (int ni = 0; ni < 4; ++ni)
                    acc[mi][ni] = __builtin_amdgcn_mfma_f32_16x16x32_bf16(
                        af[mi], bfr[ni], acc[mi][ni], 0, 0, 0);
        }
        __syncthreads();
    }

    float b1v[4], w2a[4], w2b[4];
#pragma unroll
    for (int ni = 0; ni < 4; ++ni) {
        const int cc2 = wc * 64 + ni * 16 + l15;
        b1v[ni] = b1[(size_t)s * H_DIM + cc2];
        const float* w2p = W2 + ((size_t)s * H_DIM + cc2) * 2;
        w2a[ni] = w2p[0];
        w2b[ni] = w2p[1];
    }
    float p0s[4][4], p1s[4][4];
#pragma unroll
    for (int mi = 0; mi < 4; ++mi)
#pragma unroll
        for (int r = 0; r < 4; ++r) {
            float p0 = 0.f, p1 = 0.f;
#pragma unroll
            for (int ni = 0; ni < 4; ++ni) {
                float h = acc[mi][ni][r] + b1v[ni];
                h = fmaxf(h, 0.f);
                p0 = fmaf(h, w2a[ni], p0);
                p1 = fmaf(h, w2b[ni], p1);
            }
            p0s[mi][r] = p0; p1s[mi][r] = p1;
        }
#pragma unroll
    for (int mi = 0; mi < 4; ++mi)
#pragma unroll
        for (int r = 0; r < 4; ++r) {
            p0s[mi][r] += __shfl_xor(p0s[mi][r], 1);
            p0s[mi][r] += __shfl_xor(p0s[mi][r], 2);
            p1s[mi][r] += __shfl_xor(p1s[mi][r], 1);
            p1s[mi][r] += __shfl_xor(p1s[mi][r], 2);
        }
    if ((lane & 3) == 0) {
        const int cw = wc * 4 + (l15 >> 2);
#pragma unroll
        for (int mi = 0; mi < 4; ++mi)
#pragma unroll
            for (int r = 0; r < 4; ++r) {
                const int row = wr * 64 + mi * 16 + l16 * 4 + r;
                *(float2*)(lds + 65536 + (row * 8 + (cw ^ (row & 7))) * 8)
                    = (float2){p0s[mi][r], p1s[mi][r]};
            }
    }
    __syncthreads();
    if (tid < 128) {
        const int row = tid;
        float alpha = b2[(size_t)s * 2 + 0];
        float beta  = b2[(size_t)s * 2 + 1];
#pragma unroll
        for (int cw = 0; cw < 8; ++cw) {
            const float2 v = *(const float2*)(lds + 65536 + (row * 8 + (cw ^ (row & 7))) * 8);
            alpha += v.x; beta += v.y;
        }
        const int grow = brow0 + row;
        const float phi = z[(size_t)grow * D_DIM + idx];
        const float u = tanf(0.5f * (phi - PI_F));
        const float a = expf(alpha);
        const float v = fmaf(a, u, beta);
        x_out[(size_t)grow * D_DIM + idx] = 2.0f * atanf(v) + PI_F;
        atomicAdd(ld_out + grow, alpha + log1pf(u * u) - log1pf(v * v));
        if (s_idx == 0)
            x_out[(size_t)grow * D_DIM] = z[(size_t)grow * D_DIM];
    }
}

extern "C" void kernel_launch(void* const* d_in, const int* in_sizes, int n_in,
                              void* d_out, int out_size, void* d_ws, size_t ws_size,
                              hipStream_t stream) {
    const float* z  = (const float*)d_in[0];
    const float* W1 = (const float*)d_in[1];
    const float* b1 = (const float*)d_in[2];
    const float* W2 = (const float*)d_in[3];
    const float* b2 = (const float*)d_in[4];
    float* x_out  = (float*)d_out;
    float* ld_out = x_out + (size_t)B_DIM * D_DIM;

    unsigned char* z_swz = (unsigned char*)d_ws;
    unsigned char* w1bf  = z_swz + ZSWZ_BYTES;
    const size_t need = ZSWZ_BYTES + W1BF_BYTES;

    hipMemsetAsync(ld_out, 0, B_DIM * sizeof(float), stream);
    if (ws_size >= need) {
        pack_kernel<<<dim3(256 + 4088), dim3(256), 0, stream>>>(z, W1, z_swz, w1bf);
        ar_site_kernel<true><<<dim3(512), dim3(256), 0, stream>>>(
            z, z_swz, w1bf, W1, b1, W2, b2, x_out, ld_out);
    } else {
        ar_site_kernel<false><<<dim3(4096), dim3(256), 0, stream>>>(
            z, nullptr, nullptr, W1, b1, W2, b2, x_out, ld_out);
    }
}